// Round 10
// baseline (145.822 us; speedup 1.0000x reference)
//
#include <hip/hip_runtime.h>
#include <hip/hip_bf16.h>

constexpr int Bb  = 4;
constexpr int Nn  = 1024;
constexpr int Fin = 256;
constexpr int Cc  = 256;   // H*HID
constexpr int Hh  = 8;
constexpr int Hid = 32;
constexpr float Alpha = 0.2f;
constexpr float L2E = 1.4426950408889634f;   // log2(e)
constexpr int NCHUNK = 16;                   // i-chunks for colsum partials
constexpr unsigned NBLK2 = 512;              // blocks in fused kernel (2/CU -> co-resident)

typedef __attribute__((ext_vector_type(8))) short bf16x8;
typedef __attribute__((ext_vector_type(4))) float f32x4;

__device__ __forceinline__ unsigned cvt_pk_bf16(float lo, float hi) {
    unsigned r;
    asm("v_cvt_pk_bf16_f32 %0, %1, %2" : "=v"(r) : "v"(lo), "v"(hi));
    return r;
}

// ---------------- K1: fused s = h @ W (bf16 MFMA) + ei/ej dots + sC fragment store ----
// (R7's measured-best gemm, verbatim.) grid (4 head-pairs, 64 row-tiles), 256 thr.
__global__ __launch_bounds__(256) void k_gemm(const float* __restrict__ hin,
                                              const float* __restrict__ W,
                                              const float* __restrict__ av,
                                              float* __restrict__ eiT,
                                              float* __restrict__ ejT,
                                              unsigned short* __restrict__ sC) {
    __shared__ unsigned short Asm[64 * 256];
    __shared__ unsigned short Bsm[64 * 256];
    const int t = threadIdx.x;
    const int hp = blockIdx.x;        // head-pair 0..3 (cols hp*64)
    const int rt = blockIdx.y;        // row tile 0..63
    const int b = rt >> 4;
    const int row0m = (rt & 15) * 64; // row within batch
    const int grow0 = rt * 64;        // global M row
    const int col0 = hp * 64;

    #pragma unroll
    for (int i = 0; i < 16; ++i) {
        int fi = i * 256 + t;
        int r = fi >> 6, c4 = fi & 63;
        float4 v = *reinterpret_cast<const float4*>(&hin[(size_t)(grow0 + r) * Fin + c4 * 4]);
        uint2 pk = make_uint2(cvt_pk_bf16(v.x, v.y), cvt_pk_bf16(v.z, v.w));
        *reinterpret_cast<uint2*>(reinterpret_cast<char*>(Asm) + r * 512 +
            (((c4 >> 1) ^ ((r >> 1) & 7)) << 4) + ((c4 & 1) << 3)) = pk;
    }
    #pragma unroll
    for (int i = 0; i < 32; ++i) {
        int p = i * 256 + t;
        int c = p & 63, k = (p >> 6) << 1;
        float w0 = W[(size_t)k * Cc + col0 + c];
        float w1 = W[(size_t)(k + 1) * Cc + col0 + c];
        unsigned pk = cvt_pk_bf16(w0, w1);
        *reinterpret_cast<unsigned*>(reinterpret_cast<char*>(Bsm) + c * 512 +
            (((k >> 3) ^ ((c >> 1) & 7)) << 4) + ((k & 7) << 1)) = pk;
    }
    __syncthreads();

    const int w = t >> 6, l = t & 63;
    const int lr = l & 15, lg = l >> 4;
    const int ar = w * 16 + lr;
    f32x4 acc[4] = {{0.f,0.f,0.f,0.f},{0.f,0.f,0.f,0.f},{0.f,0.f,0.f,0.f},{0.f,0.f,0.f,0.f}};

    #pragma unroll
    for (int ks = 0; ks < 8; ++ks) {
        bf16x8 af = *reinterpret_cast<const bf16x8*>(reinterpret_cast<char*>(Asm) +
            ar * 512 + ((((ks << 2) + lg) ^ ((ar >> 1) & 7)) << 4));
        #pragma unroll
        for (int n = 0; n < 4; ++n) {
            int c = n * 16 + lr;
            bf16x8 bf = *reinterpret_cast<const bf16x8*>(reinterpret_cast<char*>(Bsm) +
                c * 512 + ((((ks << 2) + lg) ^ ((c >> 1) & 7)) << 4));
            acc[n] = __builtin_amdgcn_mfma_f32_16x16x32_bf16(af, bf, acc[n], 0, 0, 0);
        }
    }

    const int jt16 = (row0m >> 4) + w;
    #pragma unroll
    for (int n = 0; n < 4; ++n) {
        int bh = b * 8 + hp * 2 + (n >> 1);
        uint2 pk = make_uint2(cvt_pk_bf16(acc[n][0], acc[n][1]),
                              cvt_pk_bf16(acc[n][2], acc[n][3]));
        *reinterpret_cast<uint2*>(reinterpret_cast<char*>(sC) +
            ((((size_t)bh * 64 + jt16) * 2 + (n & 1)) * 64 + l) * 8) = pk;
    }

    float aL0 = av[lr], aL1 = av[16 + lr], aR0 = av[32 + lr], aR1 = av[48 + lr];
    #pragma unroll
    for (int hh = 0; hh < 2; ++hh) {
        float pi[4], pj[4];
        #pragma unroll
        for (int reg = 0; reg < 4; ++reg) {
            pi[reg] = acc[hh * 2][reg] * aL0 + acc[hh * 2 + 1][reg] * aL1;
            pj[reg] = acc[hh * 2][reg] * aR0 + acc[hh * 2 + 1][reg] * aR1;
        }
        #pragma unroll
        for (int m = 1; m < 16; m <<= 1) {
            #pragma unroll
            for (int reg = 0; reg < 4; ++reg) {
                pi[reg] += __shfl_xor(pi[reg], m);
                pj[reg] += __shfl_xor(pj[reg], m);
            }
        }
        if (lr == 0) {
            int bh = b * 8 + hp * 2 + hh;
            #pragma unroll
            for (int reg = 0; reg < 4; ++reg) {
                int row = row0m + w * 16 + lg * 4 + reg;
                eiT[bh * Nn + row] = pi[reg] * L2E;
                ejT[bh * Nn + row] = pj[reg] * L2E;
            }
        }
    }
}

// ---------------- K2: persistent fused colsum + grid-barrier + MFMA aggregation ----------------
// 512 blocks x 256 thr, guaranteed co-resident (18KB LDS, <=2 waves/EU needed).
// Phase 1: each block does 2 colsum units (1024 total) -> Zp partials + adjBT.
// Software grid barrier (agent-scope acq/rel atomics -> cross-XCD L2 wb/inv).
// Phase 2: each block does 1 agg unit (Z-fold in LDS, exp2-weighted bf16 MFMA PV).
__global__ __launch_bounds__(256, 2) void k_fused(const float* __restrict__ eiT,
                                                  const float* __restrict__ ejT,
                                                  const int* __restrict__ adj,
                                                  const unsigned short* __restrict__ sC,
                                                  const float* __restrict__ bias,
                                                  float* __restrict__ Zp,
                                                  unsigned long long* __restrict__ adjBT,
                                                  unsigned* __restrict__ bar,
                                                  float* __restrict__ out) {
    __shared__ float eis[64 * Hh];         // 2 KB  (colsum)
    __shared__ float red[4 * 64 * Hh];     // 8 KB  (colsum)
    __shared__ __align__(16) float2 ez_s[Nn];  // 8 KB (agg)
    const int t = threadIdx.x;
    const int bid = blockIdx.x;

    // ---- phase 1: column sums ----
    #pragma unroll
    for (int q = 0; q < 2; ++q) {
        const int unit = (bid << 1) | q;
        const int ic = unit & 15;
        const int jt = (unit >> 4) & 15;
        const int b  = unit >> 8;
        const int i0 = ic * 64;
        const int j0 = jt * 64;
        const int jj = t & 63;
        const int g = t >> 6;
        __syncthreads();                   // protect eis/red reuse across units
        for (int v = t; v < 64 * Hh; v += 256) {
            int h = v >> 6, i = v & 63;
            eis[i * Hh + h] = eiT[((size_t)b * Hh + h) * Nn + i0 + i];
        }
        float ejr[Hh];
        #pragma unroll
        for (int hh = 0; hh < Hh; ++hh)
            ejr[hh] = ejT[((size_t)b * Hh + hh) * Nn + j0 + jj];
        __syncthreads();
        float z[Hh] = {};
        const int* ap = &adj[((size_t)b * Nn + i0 + g * 16) * Nn + j0 + jj];
        #pragma unroll 8
        for (int ii = 0; ii < 16; ++ii) {
            int a = ap[(size_t)ii * Nn];
            unsigned long long bal = __ballot(a != 0);
            if (jj == 0)
                adjBT[((size_t)b * 16 + jt) * Nn + (i0 + g * 16 + ii)] = bal;
            float mf = (float)(a != 0);
            const float* ep = &eis[(g * 16 + ii) * Hh];
            #pragma unroll
            for (int hh = 0; hh < Hh; ++hh) {
                float x = ep[hh] + ejr[hh];
                x = fmaxf(x, Alpha * x);
                z[hh] = fmaf(mf, exp2f(x), z[hh]);
            }
        }
        #pragma unroll
        for (int hh = 0; hh < Hh; ++hh)
            red[(g * 64 + jj) * Hh + hh] = z[hh];
        __syncthreads();
        for (int v = t; v < 64 * Hh; v += 256) {
            int h2 = v >> 6, jj2 = v & 63;
            float sum = red[jj2 * Hh + h2] + red[(64 + jj2) * Hh + h2] +
                        red[(128 + jj2) * Hh + h2] + red[(192 + jj2) * Hh + h2];
            Zp[(size_t)ic * (Bb * Nn * Hh) + ((size_t)b * Hh + h2) * Nn + j0 + jj2] = sum;
        }
    }

    // ---- grid barrier (all 512 blocks co-resident by construction) ----
    __syncthreads();
    if (t == 0) {
        __hip_atomic_fetch_add(bar, 1u, __ATOMIC_RELEASE, __HIP_MEMORY_SCOPE_AGENT);
        while (__hip_atomic_load(bar, __ATOMIC_ACQUIRE, __HIP_MEMORY_SCOPE_AGENT) < NBLK2)
            __builtin_amdgcn_s_sleep(2);
    }
    __syncthreads();

    // ---- phase 2: aggregation ----
    const int xcd = bid & 7, g2 = bid >> 3;
    const int bh = xcd * 4 + (g2 & 3);
    const int it = g2 >> 2;
    const int b = bh >> 3, h = bh & 7;
    const int w = t >> 6, l = t & 63;
    const int lg = l >> 4;
    const int row = it * 64 + w * 16 + (l & 15);

    #pragma unroll
    for (int q = 0; q < 4; ++q) {
        int j = q * 256 + t;
        float sum = 0.f;
        #pragma unroll
        for (int c = 0; c < NCHUNK; ++c)
            sum += Zp[(size_t)c * (Bb * Nn * Hh) + (size_t)bh * Nn + j];
        ez_s[j] = make_float2(ejT[(size_t)bh * Nn + j], 1.0f / sum);
    }
    __syncthreads();

    const float ei_r = eiT[(size_t)bh * Nn + row];
    const float4* ez4 = reinterpret_cast<const float4*>(ez_s);
    const unsigned long long* scp =
        reinterpret_cast<const unsigned long long*>(sC) + (size_t)bh * 8192;
    const int lpos = ((l >> 4) & 1) * 32 + (l & 15);

    f32x4 acc0 = {0.f, 0.f, 0.f, 0.f}, acc1 = {0.f, 0.f, 0.f, 0.f};

    for (int jk = 0; jk < 32; ++jk) {
        const int j8 = jk * 32 + lg * 8;
        float4 za = ez4[(j8 >> 1) + 0];
        float4 zb = ez4[(j8 >> 1) + 1];
        float4 zc = ez4[(j8 >> 1) + 2];
        float4 zd = ez4[(j8 >> 1) + 3];
        unsigned long long m64 = adjBT[((size_t)b * 16 + (jk >> 1)) * Nn + row];
        unsigned mb = (unsigned)(m64 >> ((jk & 1) * 32 + lg * 8)) & 0xFFu;

        float wv[8];
        {
            float ejv[8] = {za.x, za.z, zb.x, zb.z, zc.x, zc.z, zd.x, zd.z};
            float rzv[8] = {za.y, za.w, zb.y, zb.w, zc.y, zc.w, zd.y, zd.w};
            #pragma unroll
            for (int e = 0; e < 8; ++e) {
                float x = ei_r + ejv[e];
                x = fmaxf(x, Alpha * x);
                float ww = exp2f(x) * rzv[e];
                wv[e] = ((mb >> e) & 1u) ? ww : 0.0f;
            }
        }
        union { bf16x8 v; unsigned u[4]; } A;
        A.u[0] = cvt_pk_bf16(wv[0], wv[1]);
        A.u[1] = cvt_pk_bf16(wv[2], wv[3]);
        A.u[2] = cvt_pk_bf16(wv[4], wv[5]);
        A.u[3] = cvt_pk_bf16(wv[6], wv[7]);

        const int j16 = jk * 2 + (l >> 5);
        union { bf16x8 v; unsigned long long q[2]; } B0, B1;
        const unsigned long long* p0 = scp + ((size_t)j16 * 2 + 0) * 64 + lpos;
        const unsigned long long* p1 = scp + ((size_t)j16 * 2 + 1) * 64 + lpos;
        B0.q[0] = p0[0];  B0.q[1] = p0[16];
        B1.q[0] = p1[0];  B1.q[1] = p1[16];

        acc0 = __builtin_amdgcn_mfma_f32_16x16x32_bf16(A.v, B0.v, acc0, 0, 0, 0);
        acc1 = __builtin_amdgcn_mfma_f32_16x16x32_bf16(A.v, B1.v, acc1, 0, 0, 0);
    }

    const int col = l & 15;
    const float bv0 = bias[h * Hid + col];
    const float bv1 = bias[h * Hid + 16 + col];
    const int r0 = it * 64 + w * 16 + lg * 4;
    #pragma unroll
    for (int reg = 0; reg < 4; ++reg) {
        float* op = &out[((size_t)b * Nn + r0 + reg) * Cc + h * Hid];
        op[col]      = acc0[reg] + bv0;
        op[16 + col] = acc1[reg] + bv1;
    }
}

extern "C" void kernel_launch(void* const* d_in, const int* in_sizes, int n_in,
                              void* d_out, int out_size, void* d_ws, size_t ws_size,
                              hipStream_t stream) {
    const float* hin  = (const float*)d_in[0];
    const int*   adj  = (const int*)d_in[1];
    const float* W    = (const float*)d_in[2];
    const float* a    = (const float*)d_in[3];
    const float* bias = (const float*)d_in[4];
    float* out = (float*)d_out;
    float* ws  = (float*)d_ws;

    float* eiT = ws;                                      // 32,768 f32
    float* ejT = ws + 32768;                              // 32,768 f32
    float* Zp  = ws + 65536;                              // 16 x 32,768 f32
    unsigned long long* adjBT = (unsigned long long*)(ws + 589824);  // 65,536 u64
    unsigned short* sC = (unsigned short*)(ws + 1114112); // 1,048,576 bf16
    unsigned* bar = (unsigned*)(ws + 1638400);            // barrier counter

    hipMemsetAsync(bar, 0, sizeof(unsigned), stream);
    k_gemm <<<dim3(4, 64), 256, 0, stream>>>(hin, W, a, eiT, ejT, sC);
    k_fused<<<dim3(NBLK2), 256, 0, stream>>>(eiT, ejT, adj, sC, bias,
                                             Zp, adjBT, bar, out);
}

// Round 11
// 144.164 us; speedup vs baseline: 1.0115x; 1.0115x over previous
//
#include <hip/hip_runtime.h>
#include <hip/hip_bf16.h>

constexpr int Bb  = 4;
constexpr int Nn  = 1024;
constexpr int Fin = 256;
constexpr int Cc  = 256;   // H*HID
constexpr int Hh  = 8;
constexpr int Hid = 32;
constexpr float Alpha = 0.2f;
constexpr float L2E = 1.4426950408889634f;   // log2(e)
constexpr int NCHUNK = 16;                   // i-chunks for colsum partials
constexpr unsigned NBLK2 = 512;              // blocks in fused kernel (2/CU -> co-resident)

typedef __attribute__((ext_vector_type(8))) short bf16x8;
typedef __attribute__((ext_vector_type(4))) float f32x4;

__device__ __forceinline__ unsigned cvt_pk_bf16(float lo, float hi) {
    unsigned r;
    asm("v_cvt_pk_bf16_f32 %0, %1, %2" : "=v"(r) : "v"(lo), "v"(hi));
    return r;
}

// ---------------- K1: fused s = h @ W (bf16 MFMA) + ei/ej dots + sC fragment store ----
// (R7's measured-best gemm, verbatim.) grid (4 head-pairs, 64 row-tiles), 256 thr.
__global__ __launch_bounds__(256) void k_gemm(const float* __restrict__ hin,
                                              const float* __restrict__ W,
                                              const float* __restrict__ av,
                                              float* __restrict__ eiT,
                                              float* __restrict__ ejT,
                                              unsigned short* __restrict__ sC) {
    __shared__ unsigned short Asm[64 * 256];
    __shared__ unsigned short Bsm[64 * 256];
    const int t = threadIdx.x;
    const int hp = blockIdx.x;        // head-pair 0..3 (cols hp*64)
    const int rt = blockIdx.y;        // row tile 0..63
    const int b = rt >> 4;
    const int row0m = (rt & 15) * 64; // row within batch
    const int grow0 = rt * 64;        // global M row
    const int col0 = hp * 64;

    #pragma unroll
    for (int i = 0; i < 16; ++i) {
        int fi = i * 256 + t;
        int r = fi >> 6, c4 = fi & 63;
        float4 v = *reinterpret_cast<const float4*>(&hin[(size_t)(grow0 + r) * Fin + c4 * 4]);
        uint2 pk = make_uint2(cvt_pk_bf16(v.x, v.y), cvt_pk_bf16(v.z, v.w));
        *reinterpret_cast<uint2*>(reinterpret_cast<char*>(Asm) + r * 512 +
            (((c4 >> 1) ^ ((r >> 1) & 7)) << 4) + ((c4 & 1) << 3)) = pk;
    }
    #pragma unroll
    for (int i = 0; i < 32; ++i) {
        int p = i * 256 + t;
        int c = p & 63, k = (p >> 6) << 1;
        float w0 = W[(size_t)k * Cc + col0 + c];
        float w1 = W[(size_t)(k + 1) * Cc + col0 + c];
        unsigned pk = cvt_pk_bf16(w0, w1);
        *reinterpret_cast<unsigned*>(reinterpret_cast<char*>(Bsm) + c * 512 +
            (((k >> 3) ^ ((c >> 1) & 7)) << 4) + ((k & 7) << 1)) = pk;
    }
    __syncthreads();

    const int w = t >> 6, l = t & 63;
    const int lr = l & 15, lg = l >> 4;
    const int ar = w * 16 + lr;
    f32x4 acc[4] = {{0.f,0.f,0.f,0.f},{0.f,0.f,0.f,0.f},{0.f,0.f,0.f,0.f},{0.f,0.f,0.f,0.f}};

    #pragma unroll
    for (int ks = 0; ks < 8; ++ks) {
        bf16x8 af = *reinterpret_cast<const bf16x8*>(reinterpret_cast<char*>(Asm) +
            ar * 512 + ((((ks << 2) + lg) ^ ((ar >> 1) & 7)) << 4));
        #pragma unroll
        for (int n = 0; n < 4; ++n) {
            int c = n * 16 + lr;
            bf16x8 bf = *reinterpret_cast<const bf16x8*>(reinterpret_cast<char*>(Bsm) +
                c * 512 + ((((ks << 2) + lg) ^ ((c >> 1) & 7)) << 4));
            acc[n] = __builtin_amdgcn_mfma_f32_16x16x32_bf16(af, bf, acc[n], 0, 0, 0);
        }
    }

    const int jt16 = (row0m >> 4) + w;
    #pragma unroll
    for (int n = 0; n < 4; ++n) {
        int bh = b * 8 + hp * 2 + (n >> 1);
        uint2 pk = make_uint2(cvt_pk_bf16(acc[n][0], acc[n][1]),
                              cvt_pk_bf16(acc[n][2], acc[n][3]));
        *reinterpret_cast<uint2*>(reinterpret_cast<char*>(sC) +
            ((((size_t)bh * 64 + jt16) * 2 + (n & 1)) * 64 + l) * 8) = pk;
    }

    float aL0 = av[lr], aL1 = av[16 + lr], aR0 = av[32 + lr], aR1 = av[48 + lr];
    #pragma unroll
    for (int hh = 0; hh < 2; ++hh) {
        float pi[4], pj[4];
        #pragma unroll
        for (int reg = 0; reg < 4; ++reg) {
            pi[reg] = acc[hh * 2][reg] * aL0 + acc[hh * 2 + 1][reg] * aL1;
            pj[reg] = acc[hh * 2][reg] * aR0 + acc[hh * 2 + 1][reg] * aR1;
        }
        #pragma unroll
        for (int m = 1; m < 16; m <<= 1) {
            #pragma unroll
            for (int reg = 0; reg < 4; ++reg) {
                pi[reg] += __shfl_xor(pi[reg], m);
                pj[reg] += __shfl_xor(pj[reg], m);
            }
        }
        if (lr == 0) {
            int bh = b * 8 + hp * 2 + hh;
            #pragma unroll
            for (int reg = 0; reg < 4; ++reg) {
                int row = row0m + w * 16 + lg * 4 + reg;
                eiT[bh * Nn + row] = pi[reg] * L2E;
                ejT[bh * Nn + row] = pj[reg] * L2E;
            }
        }
    }
}

// ---------------- K2: persistent fused colsum + grid-barrier + MFMA aggregation ----------------
// 512 blocks x 256 thr co-resident. Barrier: release fetch_add once per block,
// RELAXED spin (no cache invalidate per poll!), single ACQUIRE load after exit.
// R10 lesson: acquire-in-spin-loop = per-poll L2 invalidate = 90us thrash.
__global__ __launch_bounds__(256, 2) void k_fused(const float* __restrict__ eiT,
                                                  const float* __restrict__ ejT,
                                                  const int* __restrict__ adj,
                                                  const unsigned short* __restrict__ sC,
                                                  const float* __restrict__ bias,
                                                  float* __restrict__ Zp,
                                                  unsigned long long* __restrict__ adjBT,
                                                  unsigned* __restrict__ bar,
                                                  float* __restrict__ out) {
    __shared__ float eis[64 * Hh];         // 2 KB  (colsum)
    __shared__ float red[4 * 64 * Hh];     // 8 KB  (colsum)
    __shared__ __align__(16) float2 ez_s[Nn];  // 8 KB (agg)
    const int t = threadIdx.x;
    const int bid = blockIdx.x;

    // ---- phase 1: column sums (2 units of 64x64 per block) ----
    #pragma unroll
    for (int q = 0; q < 2; ++q) {
        const int unit = (bid << 1) | q;
        const int ic = unit & 15;
        const int jt = (unit >> 4) & 15;
        const int b  = unit >> 8;
        const int i0 = ic * 64;
        const int j0 = jt * 64;
        const int jj = t & 63;
        const int g = t >> 6;
        __syncthreads();                   // protect eis/red reuse across units
        for (int v = t; v < 64 * Hh; v += 256) {
            int h = v >> 6, i = v & 63;
            eis[i * Hh + h] = eiT[((size_t)b * Hh + h) * Nn + i0 + i];
        }
        float ejr[Hh];
        #pragma unroll
        for (int hh = 0; hh < Hh; ++hh)
            ejr[hh] = ejT[((size_t)b * Hh + hh) * Nn + j0 + jj];
        __syncthreads();
        float z[Hh] = {};
        const int* ap = &adj[((size_t)b * Nn + i0 + g * 16) * Nn + j0 + jj];
        #pragma unroll 8
        for (int ii = 0; ii < 16; ++ii) {
            int a = ap[(size_t)ii * Nn];
            unsigned long long bal = __ballot(a != 0);
            if (jj == 0)
                adjBT[((size_t)b * 16 + jt) * Nn + (i0 + g * 16 + ii)] = bal;
            float mf = (float)(a != 0);
            const float* ep = &eis[(g * 16 + ii) * Hh];
            #pragma unroll
            for (int hh = 0; hh < Hh; ++hh) {
                float x = ep[hh] + ejr[hh];
                x = fmaxf(x, Alpha * x);
                z[hh] = fmaf(mf, exp2f(x), z[hh]);
            }
        }
        #pragma unroll
        for (int hh = 0; hh < Hh; ++hh)
            red[(g * 64 + jj) * Hh + hh] = z[hh];
        __syncthreads();
        for (int v = t; v < 64 * Hh; v += 256) {
            int h2 = v >> 6, jj2 = v & 63;
            float sum = red[jj2 * Hh + h2] + red[(64 + jj2) * Hh + h2] +
                        red[(128 + jj2) * Hh + h2] + red[(192 + jj2) * Hh + h2];
            Zp[(size_t)ic * (Bb * Nn * Hh) + ((size_t)b * Hh + h2) * Nn + j0 + jj2] = sum;
        }
    }

    // ---- grid barrier: release-add once; RELAXED spin; ONE acquire at exit ----
    __syncthreads();
    if (t == 0) {
        __hip_atomic_fetch_add(bar, 1u, __ATOMIC_RELEASE, __HIP_MEMORY_SCOPE_AGENT);
        while (__hip_atomic_load(bar, __ATOMIC_RELAXED, __HIP_MEMORY_SCOPE_AGENT) < NBLK2)
            __builtin_amdgcn_s_sleep(8);
        (void)__hip_atomic_load(bar, __ATOMIC_ACQUIRE, __HIP_MEMORY_SCOPE_AGENT);
    }
    __syncthreads();

    // ---- phase 2: aggregation ----
    const int xcd = bid & 7, g2 = bid >> 3;
    const int bh = xcd * 4 + (g2 & 3);
    const int it = g2 >> 2;
    const int b = bh >> 3, h = bh & 7;
    const int w = t >> 6, l = t & 63;
    const int lg = l >> 4;
    const int row = it * 64 + w * 16 + (l & 15);

    #pragma unroll
    for (int q = 0; q < 4; ++q) {
        int j = q * 256 + t;
        float sum = 0.f;
        #pragma unroll
        for (int c = 0; c < NCHUNK; ++c)
            sum += Zp[(size_t)c * (Bb * Nn * Hh) + (size_t)bh * Nn + j];
        ez_s[j] = make_float2(ejT[(size_t)bh * Nn + j], 1.0f / sum);
    }
    __syncthreads();

    const float ei_r = eiT[(size_t)bh * Nn + row];
    const float4* ez4 = reinterpret_cast<const float4*>(ez_s);
    const unsigned long long* scp =
        reinterpret_cast<const unsigned long long*>(sC) + (size_t)bh * 8192;
    const int lpos = ((l >> 4) & 1) * 32 + (l & 15);

    f32x4 acc0 = {0.f, 0.f, 0.f, 0.f}, acc1 = {0.f, 0.f, 0.f, 0.f};

    for (int jk = 0; jk < 32; ++jk) {
        const int j8 = jk * 32 + lg * 8;
        float4 za = ez4[(j8 >> 1) + 0];
        float4 zb = ez4[(j8 >> 1) + 1];
        float4 zc = ez4[(j8 >> 1) + 2];
        float4 zd = ez4[(j8 >> 1) + 3];
        unsigned long long m64 = adjBT[((size_t)b * 16 + (jk >> 1)) * Nn + row];
        unsigned mb = (unsigned)(m64 >> ((jk & 1) * 32 + lg * 8)) & 0xFFu;

        float wv[8];
        {
            float ejv[8] = {za.x, za.z, zb.x, zb.z, zc.x, zc.z, zd.x, zd.z};
            float rzv[8] = {za.y, za.w, zb.y, zb.w, zc.y, zc.w, zd.y, zd.w};
            #pragma unroll
            for (int e = 0; e < 8; ++e) {
                float x = ei_r + ejv[e];
                x = fmaxf(x, Alpha * x);
                float ww = exp2f(x) * rzv[e];
                wv[e] = ((mb >> e) & 1u) ? ww : 0.0f;
            }
        }
        union { bf16x8 v; unsigned u[4]; } A;
        A.u[0] = cvt_pk_bf16(wv[0], wv[1]);
        A.u[1] = cvt_pk_bf16(wv[2], wv[3]);
        A.u[2] = cvt_pk_bf16(wv[4], wv[5]);
        A.u[3] = cvt_pk_bf16(wv[6], wv[7]);

        const int j16 = jk * 2 + (l >> 5);
        union { bf16x8 v; unsigned long long q[2]; } B0, B1;
        const unsigned long long* p0 = scp + ((size_t)j16 * 2 + 0) * 64 + lpos;
        const unsigned long long* p1 = scp + ((size_t)j16 * 2 + 1) * 64 + lpos;
        B0.q[0] = p0[0];  B0.q[1] = p0[16];
        B1.q[0] = p1[0];  B1.q[1] = p1[16];

        acc0 = __builtin_amdgcn_mfma_f32_16x16x32_bf16(A.v, B0.v, acc0, 0, 0, 0);
        acc1 = __builtin_amdgcn_mfma_f32_16x16x32_bf16(A.v, B1.v, acc1, 0, 0, 0);
    }

    const int col = l & 15;
    const float bv0 = bias[h * Hid + col];
    const float bv1 = bias[h * Hid + 16 + col];
    const int r0 = it * 64 + w * 16 + lg * 4;
    #pragma unroll
    for (int reg = 0; reg < 4; ++reg) {
        float* op = &out[((size_t)b * Nn + r0 + reg) * Cc + h * Hid];
        op[col]      = acc0[reg] + bv0;
        op[16 + col] = acc1[reg] + bv1;
    }
}

extern "C" void kernel_launch(void* const* d_in, const int* in_sizes, int n_in,
                              void* d_out, int out_size, void* d_ws, size_t ws_size,
                              hipStream_t stream) {
    const float* hin  = (const float*)d_in[0];
    const int*   adj  = (const int*)d_in[1];
    const float* W    = (const float*)d_in[2];
    const float* a    = (const float*)d_in[3];
    const float* bias = (const float*)d_in[4];
    float* out = (float*)d_out;
    float* ws  = (float*)d_ws;

    float* eiT = ws;                                      // 32,768 f32
    float* ejT = ws + 32768;                              // 32,768 f32
    float* Zp  = ws + 65536;                              // 16 x 32,768 f32
    unsigned long long* adjBT = (unsigned long long*)(ws + 589824);  // 65,536 u64
    unsigned short* sC = (unsigned short*)(ws + 1114112); // 1,048,576 bf16
    unsigned* bar = (unsigned*)(ws + 1638400);            // barrier counter

    hipMemsetAsync(bar, 0, sizeof(unsigned), stream);
    k_gemm <<<dim3(4, 64), 256, 0, stream>>>(hin, W, a, eiT, ejT, sC);
    k_fused<<<dim3(NBLK2), 256, 0, stream>>>(eiT, ejT, adj, sC, bias,
                                             Zp, adjBT, bar, out);
}

// Round 12
// 117.082 us; speedup vs baseline: 1.2455x; 1.2313x over previous
//
#include <hip/hip_runtime.h>
#include <hip/hip_bf16.h>

constexpr int Bb  = 4;
constexpr int Nn  = 1024;
constexpr int Fin = 256;
constexpr int Cc  = 256;   // H*HID
constexpr int Hh  = 8;
constexpr int Hid = 32;
constexpr float Alpha = 0.2f;
constexpr float L2E = 1.4426950408889634f;   // log2(e)
constexpr int NCHUNK = 16;                   // i-chunks for colsum partials

typedef __attribute__((ext_vector_type(8))) short bf16x8;
typedef __attribute__((ext_vector_type(4))) float f32x4;

__device__ __forceinline__ unsigned cvt_pk_bf16(float lo, float hi) {
    unsigned r;
    asm("v_cvt_pk_bf16_f32 %0, %1, %2" : "=v"(r) : "v"(lo), "v"(hi));
    return r;
}

// ---------------- K0: pack adj -> transposed bitmask (pure streaming, no compute) ----------
// 2048 blocks x 4 waves x 8 rows: each wave-iter = 1 coalesced 256B load + ballot + 8B store.
// No FMA chain between loads -> loads pipeline at full BW (R11 lesson: colsum's fused
// load->ballot->exp chain held adj reads to ~400 GB/s for 40us; decouple them).
__global__ __launch_bounds__(256) void k_pack(const int* __restrict__ adj,
                                              unsigned long long* __restrict__ adjBT) {
    const int t = threadIdx.x, w = t >> 6, jj = t & 63;
    const int blk = blockIdx.x;            // [b(4)][jt(16)][ib(32)]
    const int b  = blk >> 9;
    const int jt = (blk >> 5) & 15;
    const int ib = blk & 31;
    const int i0 = ib * 32 + w * 8;
    const int* ap = adj + ((size_t)(b * Nn + i0) << 10) + jt * 64 + jj;
    unsigned long long* op = adjBT + (((size_t)b * 16 + jt) << 10) + i0;
    #pragma unroll
    for (int k = 0; k < 8; ++k) {
        int a = ap[(size_t)k << 10];
        unsigned long long m = __ballot(a != 0);
        if (jj == 0) op[k] = m;
    }
}

// ---------------- K1: fused s = h @ W (bf16 MFMA) + ei/ej dots + sC fragment store ----
// (R7's measured-best gemm, verbatim.)
__global__ __launch_bounds__(256) void k_gemm(const float* __restrict__ hin,
                                              const float* __restrict__ W,
                                              const float* __restrict__ av,
                                              float* __restrict__ eiT,
                                              float* __restrict__ ejT,
                                              unsigned short* __restrict__ sC) {
    __shared__ unsigned short Asm[64 * 256];
    __shared__ unsigned short Bsm[64 * 256];
    const int t = threadIdx.x;
    const int hp = blockIdx.x;
    const int rt = blockIdx.y;
    const int b = rt >> 4;
    const int row0m = (rt & 15) * 64;
    const int grow0 = rt * 64;
    const int col0 = hp * 64;

    #pragma unroll
    for (int i = 0; i < 16; ++i) {
        int fi = i * 256 + t;
        int r = fi >> 6, c4 = fi & 63;
        float4 v = *reinterpret_cast<const float4*>(&hin[(size_t)(grow0 + r) * Fin + c4 * 4]);
        uint2 pk = make_uint2(cvt_pk_bf16(v.x, v.y), cvt_pk_bf16(v.z, v.w));
        *reinterpret_cast<uint2*>(reinterpret_cast<char*>(Asm) + r * 512 +
            (((c4 >> 1) ^ ((r >> 1) & 7)) << 4) + ((c4 & 1) << 3)) = pk;
    }
    #pragma unroll
    for (int i = 0; i < 32; ++i) {
        int p = i * 256 + t;
        int c = p & 63, k = (p >> 6) << 1;
        float w0 = W[(size_t)k * Cc + col0 + c];
        float w1 = W[(size_t)(k + 1) * Cc + col0 + c];
        unsigned pk = cvt_pk_bf16(w0, w1);
        *reinterpret_cast<unsigned*>(reinterpret_cast<char*>(Bsm) + c * 512 +
            (((k >> 3) ^ ((c >> 1) & 7)) << 4) + ((k & 7) << 1)) = pk;
    }
    __syncthreads();

    const int w = t >> 6, l = t & 63;
    const int lr = l & 15, lg = l >> 4;
    const int ar = w * 16 + lr;
    f32x4 acc[4] = {{0.f,0.f,0.f,0.f},{0.f,0.f,0.f,0.f},{0.f,0.f,0.f,0.f},{0.f,0.f,0.f,0.f}};

    #pragma unroll
    for (int ks = 0; ks < 8; ++ks) {
        bf16x8 af = *reinterpret_cast<const bf16x8*>(reinterpret_cast<char*>(Asm) +
            ar * 512 + ((((ks << 2) + lg) ^ ((ar >> 1) & 7)) << 4));
        #pragma unroll
        for (int n = 0; n < 4; ++n) {
            int c = n * 16 + lr;
            bf16x8 bf = *reinterpret_cast<const bf16x8*>(reinterpret_cast<char*>(Bsm) +
                c * 512 + ((((ks << 2) + lg) ^ ((c >> 1) & 7)) << 4));
            acc[n] = __builtin_amdgcn_mfma_f32_16x16x32_bf16(af, bf, acc[n], 0, 0, 0);
        }
    }

    const int jt16 = (row0m >> 4) + w;
    #pragma unroll
    for (int n = 0; n < 4; ++n) {
        int bh = b * 8 + hp * 2 + (n >> 1);
        uint2 pk = make_uint2(cvt_pk_bf16(acc[n][0], acc[n][1]),
                              cvt_pk_bf16(acc[n][2], acc[n][3]));
        *reinterpret_cast<uint2*>(reinterpret_cast<char*>(sC) +
            ((((size_t)bh * 64 + jt16) * 2 + (n & 1)) * 64 + l) * 8) = pk;
    }

    float aL0 = av[lr], aL1 = av[16 + lr], aR0 = av[32 + lr], aR1 = av[48 + lr];
    #pragma unroll
    for (int hh = 0; hh < 2; ++hh) {
        float pi[4], pj[4];
        #pragma unroll
        for (int reg = 0; reg < 4; ++reg) {
            pi[reg] = acc[hh * 2][reg] * aL0 + acc[hh * 2 + 1][reg] * aL1;
            pj[reg] = acc[hh * 2][reg] * aR0 + acc[hh * 2 + 1][reg] * aR1;
        }
        #pragma unroll
        for (int m = 1; m < 16; m <<= 1) {
            #pragma unroll
            for (int reg = 0; reg < 4; ++reg) {
                pi[reg] += __shfl_xor(pi[reg], m);
                pj[reg] += __shfl_xor(pj[reg], m);
            }
        }
        if (lr == 0) {
            int bh = b * 8 + hp * 2 + hh;
            #pragma unroll
            for (int reg = 0; reg < 4; ++reg) {
                int row = row0m + w * 16 + lg * 4 + reg;
                eiT[bh * Nn + row] = pi[reg] * L2E;
                ejT[bh * Nn + row] = pj[reg] * L2E;
            }
        }
    }
}

// ---------------- K2: column sums Z[b,j,h] from BITMASK (no adj reads) ----------------
// grid (16 ic, 16 jt, 4 b). Mask: wave-uniform u64 s_load (L2-hot 512KB) + per-lane bit.
__global__ __launch_bounds__(256) void k_colsum(const float* __restrict__ eiT,
                                                const float* __restrict__ ejT,
                                                const unsigned long long* __restrict__ adjBT,
                                                float* __restrict__ Zp) {
    const int ic = blockIdx.x;
    const int jt = blockIdx.y;
    const int b  = blockIdx.z;
    const int i0 = ic * 64;
    const int j0 = jt * 64;
    const int t = threadIdx.x;
    const int jj = t & 63;
    const int g = t >> 6;
    __shared__ float eis[64 * Hh];         // [i][h]
    __shared__ float red[4 * 64 * Hh];
    for (int v = t; v < 64 * Hh; v += 256) {
        int h = v >> 6, i = v & 63;
        eis[i * Hh + h] = eiT[((size_t)b * Hh + h) * Nn + i0 + i];
    }
    float ejr[Hh];
    #pragma unroll
    for (int hh = 0; hh < Hh; ++hh)
        ejr[hh] = ejT[((size_t)b * Hh + hh) * Nn + j0 + jj];
    __syncthreads();
    float z[Hh] = {};
    const unsigned long long* mp = adjBT + (((size_t)b * 16 + jt) << 10) + i0 + g * 16;
    #pragma unroll 4
    for (int ii = 0; ii < 16; ++ii) {
        unsigned long long m64 = mp[ii];               // uniform -> s_load, L2-hot
        float mf = (float)((unsigned)(m64 >> jj) & 1u);
        float4 e0 = *reinterpret_cast<const float4*>(&eis[(g * 16 + ii) * Hh]);
        float4 e1 = *reinterpret_cast<const float4*>(&eis[(g * 16 + ii) * Hh + 4]);
        float ev[8] = {e0.x, e0.y, e0.z, e0.w, e1.x, e1.y, e1.z, e1.w};
        #pragma unroll
        for (int hh = 0; hh < Hh; ++hh) {
            float x = ev[hh] + ejr[hh];
            x = fmaxf(x, Alpha * x);
            z[hh] = fmaf(mf, exp2f(x), z[hh]);
        }
    }
    #pragma unroll
    for (int hh = 0; hh < Hh; ++hh)
        red[(g * 64 + jj) * Hh + hh] = z[hh];
    __syncthreads();
    for (int v = t; v < 64 * Hh; v += 256) {
        float sum = red[v] + red[512 + v] + red[1024 + v] + red[1536 + v];
        Zp[(size_t)ic * (Bb * Nn * Hh) + ((size_t)b * Nn + j0) * Hh + v] = sum;
    }
}

// ---------------- K3: transposed tables: ezrT[bh][j]={ej,1/Z} (R7 verbatim) --------
__global__ void k_ezrT(const float* __restrict__ Zp, const float* __restrict__ ejT,
                       float2* __restrict__ ezrT) {
    const int tid = blockIdx.x * 256 + threadIdx.x;   // [bh][n], 32768
    const int n = tid & 1023;
    const int bh = tid >> 10;
    const int b = bh >> 3, h = bh & 7;
    const int src = (b * Nn + n) * Hh + h;
    constexpr int S = Bb * Nn * Hh;
    float sum = 0.f;
    #pragma unroll
    for (int c = 0; c < NCHUNK; ++c) sum += Zp[(size_t)c * S + src];
    ezrT[tid] = make_float2(ejT[tid], 1.0f / sum);
}

// ---------------- K4: MFMA aggregation (R7 verbatim) ----------------
__global__ __launch_bounds__(256) void k_agg(const unsigned short* __restrict__ sC,
                                             const float* __restrict__ eiT,
                                             const float2* __restrict__ ezrT,
                                             const unsigned long long* __restrict__ adjBT,
                                             const float* __restrict__ bias,
                                             float* __restrict__ out) {
    const int bid = blockIdx.x;
    const int xcd = bid & 7, g = bid >> 3;
    const int bh = xcd * 4 + (g & 3);
    const int it = g >> 2;
    const int b = bh >> 3, h = bh & 7;
    const int t = threadIdx.x, w = t >> 6, l = t & 63;
    const int lg = l >> 4;
    const int row = it * 64 + w * 16 + (l & 15);
    const float ei_r = eiT[bh * Nn + row];

    const float4* ez4 = reinterpret_cast<const float4*>(ezrT + (size_t)bh * Nn);
    const unsigned long long* scp =
        reinterpret_cast<const unsigned long long*>(sC) + (size_t)bh * 8192;
    const int lpos = ((l >> 4) & 1) * 32 + (l & 15);

    f32x4 acc0 = {0.f, 0.f, 0.f, 0.f}, acc1 = {0.f, 0.f, 0.f, 0.f};

    for (int jk = 0; jk < 32; ++jk) {
        const int j8 = jk * 32 + lg * 8;
        float4 za = ez4[(j8 >> 1) + 0];
        float4 zb = ez4[(j8 >> 1) + 1];
        float4 zc = ez4[(j8 >> 1) + 2];
        float4 zd = ez4[(j8 >> 1) + 3];
        unsigned long long m64 = adjBT[((size_t)b * 16 + (jk >> 1)) * Nn + row];
        unsigned mb = (unsigned)(m64 >> ((jk & 1) * 32 + lg * 8)) & 0xFFu;

        float wv[8];
        {
            float ejv[8] = {za.x, za.z, zb.x, zb.z, zc.x, zc.z, zd.x, zd.z};
            float rzv[8] = {za.y, za.w, zb.y, zb.w, zc.y, zc.w, zd.y, zd.w};
            #pragma unroll
            for (int e = 0; e < 8; ++e) {
                float x = ei_r + ejv[e];
                x = fmaxf(x, Alpha * x);
                float ww = exp2f(x) * rzv[e];
                wv[e] = ((mb >> e) & 1u) ? ww : 0.0f;
            }
        }
        union { bf16x8 v; unsigned u[4]; } A;
        A.u[0] = cvt_pk_bf16(wv[0], wv[1]);
        A.u[1] = cvt_pk_bf16(wv[2], wv[3]);
        A.u[2] = cvt_pk_bf16(wv[4], wv[5]);
        A.u[3] = cvt_pk_bf16(wv[6], wv[7]);

        const int j16 = jk * 2 + (l >> 5);
        union { bf16x8 v; unsigned long long q[2]; } B0, B1;
        const unsigned long long* p0 = scp + ((size_t)j16 * 2 + 0) * 64 + lpos;
        const unsigned long long* p1 = scp + ((size_t)j16 * 2 + 1) * 64 + lpos;
        B0.q[0] = p0[0];  B0.q[1] = p0[16];
        B1.q[0] = p1[0];  B1.q[1] = p1[16];

        acc0 = __builtin_amdgcn_mfma_f32_16x16x32_bf16(A.v, B0.v, acc0, 0, 0, 0);
        acc1 = __builtin_amdgcn_mfma_f32_16x16x32_bf16(A.v, B1.v, acc1, 0, 0, 0);
    }

    const int col = l & 15;
    const float bv0 = bias[h * Hid + col];
    const float bv1 = bias[h * Hid + 16 + col];
    const int r0 = it * 64 + w * 16 + lg * 4;
    #pragma unroll
    for (int reg = 0; reg < 4; ++reg) {
        float* op = &out[((size_t)b * Nn + r0 + reg) * Cc + h * Hid];
        op[col]      = acc0[reg] + bv0;
        op[16 + col] = acc1[reg] + bv1;
    }
}

extern "C" void kernel_launch(void* const* d_in, const int* in_sizes, int n_in,
                              void* d_out, int out_size, void* d_ws, size_t ws_size,
                              hipStream_t stream) {
    const float* hin  = (const float*)d_in[0];
    const int*   adj  = (const int*)d_in[1];
    const float* W    = (const float*)d_in[2];
    const float* a    = (const float*)d_in[3];
    const float* bias = (const float*)d_in[4];
    float* out = (float*)d_out;
    float* ws  = (float*)d_ws;

    float*  eiT  = ws;                                    // 32,768 f32
    float*  ejT  = ws + 32768;                            // 32,768 f32
    float*  Zp   = ws + 65536;                            // 16 x 32,768 f32
    float2* ezrT = (float2*)(ws + 589824);                // 32,768 float2
    unsigned long long* adjBT = (unsigned long long*)(ws + 655360);  // 65,536 u64
    unsigned short* sC = (unsigned short*)(ws + 786432);  // 1,048,576 bf16

    k_pack  <<<dim3(2048),                 256, 0, stream>>>(adj, adjBT);
    k_gemm  <<<dim3(4, 64),                256, 0, stream>>>(hin, W, a, eiT, ejT, sC);
    k_colsum<<<dim3(16, 16, 4),            256, 0, stream>>>(eiT, ejT, adjBT, Zp);
    k_ezrT  <<<dim3((Bb * Nn * Hh) / 256), 256, 0, stream>>>(Zp, ejT, ezrT);
    k_agg   <<<dim3(512),                  256, 0, stream>>>(sC, eiT, ezrT, adjBT, bias, out);
}